// Round 19
// baseline (180.658 us; speedup 1.0000x reference)
//
#include <hip/hip_runtime.h>
#include <hip/hip_bf16.h>

typedef __attribute__((ext_vector_type(8))) short bf16x8;
typedef __attribute__((ext_vector_type(4))) float f32x4;
typedef unsigned long long u64;
typedef unsigned int u32;

#define MFMA(a,b,c) __builtin_amdgcn_mfma_f32_16x16x32_bf16(a,b,c,0,0,0)
#define NEG_INF (-__builtin_inff())
#define SCALE2 0.1803368801111244f   // 0.125 * log2(e)

__device__ __forceinline__ unsigned short f2b(float f) {
  unsigned int u = __float_as_uint(f);
  u = u + 0x7fffu + ((u >> 16) & 1u);
  return (unsigned short)(u >> 16);
}

__device__ __forceinline__ float b2f(unsigned short s) {
  unsigned int u = ((unsigned int)s) << 16;
  return __uint_as_float(u);
}

__device__ __forceinline__ u32 pkbf(float lo, float hi) {
  __hip_bfloat162 h = __float22bfloat162_rn(float2{lo, hi});
  return *reinterpret_cast<u32*>(&h);
}

__device__ __forceinline__ void gload_lds16(const unsigned short* g, unsigned short* l) {
  __builtin_amdgcn_global_load_lds((const __attribute__((address_space(1))) void*)g,
                                   (__attribute__((address_space(3))) void*)l, 16, 0, 0);
}

// ---------------- fused fp32 -> bf16 conversion for all 7 tensors ----------------
__global__ void cvt7(const float* s0, const float* s1, const float* s2,
                     const float* s3, const float* s4, const float* s5, const float* s6,
                     unsigned short* d0, unsigned short* d1, unsigned short* d2,
                     unsigned short* d3, unsigned short* d4, unsigned short* d5, unsigned short* d6,
                     int nbig, int nsmall) {
  const float* s; unsigned short* d; int n4;
  switch (blockIdx.y) {
    case 0: s=s0; d=d0; n4=nbig; break;
    case 1: s=s1; d=d1; n4=nbig; break;
    case 2: s=s2; d=d2; n4=nbig; break;
    case 3: s=s3; d=d3; n4=nsmall; break;
    case 4: s=s4; d=d4; n4=nsmall; break;
    case 5: s=s5; d=d5; n4=nsmall; break;
    default: s=s6; d=d6; n4=nsmall; break;
  }
  int i = blockIdx.x * blockDim.x + threadIdx.x;
  if (i < n4) {
    float4 v = reinterpret_cast<const float4*>(s)[i];
    ushort4 o;
    o.x = f2b(v.x); o.y = f2b(v.y); o.z = f2b(v.z); o.w = f2b(v.w);
    reinterpret_cast<ushort4*>(d)[i] = o;
  }
}

// ---------------- pack bool mask into bits ----------------
__global__ void pack_mask(const unsigned char* __restrict__ am, u64* __restrict__ pm, int nU) {
  int lane = threadIdx.x & 63;
  int wid = blockIdx.x * (blockDim.x >> 6) + (threadIdx.x >> 6);
  int stride = gridDim.x * (blockDim.x >> 6);
  for (int u = wid; u < nU; u += stride) {
    unsigned char v = am[(size_t)u * 64 + lane];
    u64 m = __ballot(v != 0);
    if (lane == 0) pm[u] = m;
  }
}

// ---------------- per-row tile summary ----------------
__global__ void mask_summary(const u64* __restrict__ pm, u32* __restrict__ ms, int rows, int nkt) {
  int lane = threadIdx.x & 63;
  int wid = (blockIdx.x * blockDim.x + threadIdx.x) >> 6;
  int nw = (gridDim.x * blockDim.x) >> 6;
  for (int rp = wid; rp < (rows >> 1); rp += nw) {
    int row = rp * 2 + (lane >> 5);
    int t = lane & 31;
    u64 v = pm[(size_t)row * nkt + t];
    u64 bm = __ballot(v != 0ULL);
    if (lane == 0)  ms[rp*2]     = (u32)bm;
    if (lane == 32) ms[rp*2 + 1] = (u32)(bm >> 32);
  }
}

// ---------------- merged QKV projection, 128x128 tile, single-buffer (m97) ----------------
__global__ __launch_bounds__(256) void qkv128s(
    const unsigned short* __restrict__ A,
    const unsigned short* __restrict__ Bw,
    unsigned short* __restrict__ Cqk,
    unsigned short* __restrict__ Cv)
{
  const int K = 1024;
  __shared__ unsigned short As[128*32];
  __shared__ unsigned short Bs[128*32];
  const int tid  = threadIdx.x;
  const int w    = tid >> 6, lane = tid & 63;
  const int wr   = w >> 1,   wc   = w & 1;
  const int g    = lane >> 4, li  = lane & 15;
  const int m0   = blockIdx.x * 128, n0 = blockIdx.y * 128;
  const int bq0  = (m0 >> 12) * 1024 + n0;

  f32x4 acc[4][4] = {};

  const int rS0 = (w*2+0)*16 + (lane>>2);
  const int rS1 = (w*2+1)*16 + (lane>>2);
  const int cS  = (lane&3)*8;
  const unsigned short* gA0 = A  + (size_t)(m0+rS0)*K + cS;
  const unsigned short* gA1 = A  + (size_t)(m0+rS1)*K + cS;
  const unsigned short* gB0 = Bw + (size_t)(bq0+rS0)*K + cS;
  const unsigned short* gB1 = Bw + (size_t)(bq0+rS1)*K + cS;
  unsigned short* lA0 = &As[(w*2+0)*512];
  unsigned short* lA1 = &As[(w*2+1)*512];
  unsigned short* lB0 = &Bs[(w*2+0)*512];
  unsigned short* lB1 = &Bs[(w*2+1)*512];

  for (int k0 = 0; k0 < K; k0 += 32) {
    gload_lds16(gA0 + k0, lA0);
    gload_lds16(gA1 + k0, lA1);
    gload_lds16(gB0 + k0, lB0);
    gload_lds16(gB1 + k0, lB1);
    __syncthreads();

    bf16x8 af[4], bf[4];
    #pragma unroll
    for (int i = 0; i < 4; ++i)
      af[i] = *(const bf16x8*)(&As[(wr*64 + i*16 + li)*32 + g*8]);
    #pragma unroll
    for (int j = 0; j < 4; ++j)
      bf[j] = *(const bf16x8*)(&Bs[(wc*64 + j*16 + li)*32 + g*8]);
    #pragma unroll
    for (int i = 0; i < 4; ++i)
      #pragma unroll
      for (int j = 0; j < 4; ++j)
        acc[i][j] = MFMA(af[i], bf[j], acc[i][j]);
    __syncthreads();
  }

  #pragma unroll
  for (int i = 0; i < 4; ++i) {
    #pragma unroll
    for (int j = 0; j < 4; ++j) {
      int col = n0 + wc*64 + j*16 + li;
      #pragma unroll
      for (int r = 0; r < 4; ++r) {
        int row = m0 + wr*64 + i*16 + g*4 + r;
        float v = acc[i][j][r];
        if (row < 8192) {
          size_t addr = (((size_t)(row >> 11) * 16 + (col >> 6)) * 2048 + (row & 2047)) * 64 + (col & 63);
          Cqk[addr] = f2b(v);
        } else {
          int tk = row & 4095;
          size_t addr = (((size_t)(tk >> 11) * 16 + (col >> 6)) * 64 + (col & 63)) * 2048 + (tk & 2047);
          Cv[addr] = f2b(v);
        }
      }
    }
  }
}

// ---------------- final projection GEMM, 64x64 tile, 2-phase dbuf ----------------
__global__ __launch_bounds__(256) void gemm64x64(
    const unsigned short* __restrict__ A,
    const unsigned short* __restrict__ Bw,
    float* __restrict__ Cf,
    const float* __restrict__ bias,
    int M, int N, int K)
{
  const int NT = 32;
  __shared__ unsigned short As[2][64*32];
  __shared__ unsigned short Bs[2][64*32];
  const int tid  = threadIdx.x;
  const int w    = tid >> 6, lane = tid & 63;
  const int wr   = w >> 1,   wc   = w & 1;
  const int g    = lane >> 4, li  = lane & 15;
  const int m0   = blockIdx.x * 64, n0 = blockIdx.y * 64;

  f32x4 acc[2][2] = {};
  const int crow = lane >> 2, ccol = (lane & 3) * 8;
  const unsigned short* gA = A  + (size_t)(m0 + w*16 + crow)*K + ccol;
  const unsigned short* gB = Bw + (size_t)(n0 + w*16 + crow)*K + ccol;

  gload_lds16(gA, &As[0][w*512]);
  gload_lds16(gB, &Bs[0][w*512]);
  __syncthreads();

  for (int t = 0; t < NT; ++t) {
    const int cur = t & 1;
    if (t + 1 < NT) {
      const int k1 = (t + 1) * 32;
      gload_lds16(gA + k1, &As[cur^1][w*512]);
      gload_lds16(gB + k1, &Bs[cur^1][w*512]);
    }
    bf16x8 af[2], bf[2];
    #pragma unroll
    for (int i = 0; i < 2; ++i)
      af[i] = *(const bf16x8*)(&As[cur][(wr*32 + i*16 + li)*32 + g*8]);
    #pragma unroll
    for (int j = 0; j < 2; ++j)
      bf[j] = *(const bf16x8*)(&Bs[cur][(wc*32 + j*16 + li)*32 + g*8]);
    #pragma unroll
    for (int i = 0; i < 2; ++i)
      #pragma unroll
      for (int j = 0; j < 2; ++j)
        acc[i][j] = MFMA(af[i], bf[j], acc[i][j]);
    __syncthreads();
  }

  #pragma unroll
  for (int i = 0; i < 2; ++i) {
    #pragma unroll
    for (int j = 0; j < 2; ++j) {
      int col = n0 + wc*32 + j*16 + li;
      #pragma unroll
      for (int r = 0; r < 4; ++r) {
        int row = m0 + wr*32 + i*16 + g*4 + r;
        Cf[(size_t)row*N + col] = acc[i][j][r] + bias[col];
      }
    }
  }
}

// ---------------- per-tile attention step (proven, verbatim) ----------------
__device__ __forceinline__ void attn_tile(
    const unsigned short* __restrict__ Ks, const unsigned short* __restrict__ Vts,
    const bf16x8& qf0, const bf16x8& qf1,
    float& mrun, float& lrun, f32x4* oacc,
    bool edge, bool doMask, const u64* __restrict__ prow,
    int t, int kv0, int qg, int g, int li)
{
  f32x4 sa[4];
  #pragma unroll
  for (int ni = 0; ni < 4; ++ni) sa[ni] = (f32x4){0.f, 0.f, 0.f, 0.f};
  #pragma unroll
  for (int ni = 0; ni < 4; ++ni) {
    int row = ni*16 + li, rx = row & 7;
    bf16x8 k0 = *(const bf16x8*)(&Ks[row*64 + ((g     ^ rx))*8]);
    bf16x8 k1 = *(const bf16x8*)(&Ks[row*64 + (((4+g) ^ rx))*8]);
    sa[ni] = MFMA(k0, qf0, sa[ni]);
    sa[ni] = MFMA(k1, qf1, sa[ni]);
  }

  float corr = 1.0f;
  bool rescale = true;

  if (!edge && !doMask) {
    float pe[4][4];
    #pragma unroll
    for (int ni = 0; ni < 4; ++ni)
      #pragma unroll
      for (int r = 0; r < 4; ++r)
        pe[ni][r] = exp2f(fmaf(sa[ni][r], SCALE2, -mrun));
    float a0 = fmaxf(sa[0][0], sa[0][1]), a1 = fmaxf(sa[0][2], sa[0][3]);
    float a2 = fmaxf(sa[1][0], sa[1][1]), a3 = fmaxf(sa[1][2], sa[1][3]);
    float a4 = fmaxf(sa[2][0], sa[2][1]), a5 = fmaxf(sa[2][2], sa[2][3]);
    float a6 = fmaxf(sa[3][0], sa[3][1]), a7 = fmaxf(sa[3][2], sa[3][3]);
    float mx = fmaxf(fmaxf(fmaxf(a0,a1), fmaxf(a2,a3)),
                     fmaxf(fmaxf(a4,a5), fmaxf(a6,a7)));
    mx = fmaxf(mx, __shfl_xor(mx, 16));
    mx = fmaxf(mx, __shfl_xor(mx, 32));
    float mxs = mx * SCALE2;
    if (__all(mxs <= mrun + 8.0f)) {
      float s0 = (pe[0][0]+pe[0][1]) + (pe[0][2]+pe[0][3]);
      float s1 = (pe[1][0]+pe[1][1]) + (pe[1][2]+pe[1][3]);
      float s2 = (pe[2][0]+pe[2][1]) + (pe[2][2]+pe[2][3]);
      float s3 = (pe[3][0]+pe[3][1]) + (pe[3][2]+pe[3][3]);
      float rs = (s0+s1) + (s2+s3);
      rs += __shfl_xor(rs, 16);
      rs += __shfl_xor(rs, 32);
      lrun += rs;
      #pragma unroll
      for (int ni = 0; ni < 4; ++ni)
        #pragma unroll
        for (int r = 0; r < 4; ++r)
          sa[ni][r] = pe[ni][r];
      rescale = false;
    } else {
      float mu = fmaxf(mrun, mxs);
      corr = exp2f(mrun - mu);
      float rs = 0.f;
      #pragma unroll
      for (int ni = 0; ni < 4; ++ni)
        #pragma unroll
        for (int r = 0; r < 4; ++r) {
          float p = exp2f(fmaf(sa[ni][r], SCALE2, -mu));
          sa[ni][r] = p;
          rs += p;
        }
      rs += __shfl_xor(rs, 16);
      rs += __shfl_xor(rs, 32);
      lrun = lrun * corr + rs;
      mrun = mu;
    }
  } else {
    u64 mrow = doMask ? prow[t] : 0ULL;
    #pragma unroll
    for (int ni = 0; ni < 4; ++ni)
      #pragma unroll
      for (int r = 0; r < 4; ++r) {
        int kvloc = ni*16 + g*4 + r;
        bool dead = (edge && (kv0 + kvloc > qg)) || ((mrow >> kvloc) & 1ULL);
        sa[ni][r] = dead ? NEG_INF : sa[ni][r] * SCALE2;
      }
    float mx = sa[0][0];
    #pragma unroll
    for (int ni = 0; ni < 4; ++ni)
      #pragma unroll
      for (int r = 0; r < 4; ++r)
        if (ni + r) mx = fmaxf(mx, sa[ni][r]);
    mx = fmaxf(mx, __shfl_xor(mx, 16));
    mx = fmaxf(mx, __shfl_xor(mx, 32));
    float mu = fmaxf(mrun, mx);
    corr = exp2f(mrun - mu);
    float rs = 0.f;
    #pragma unroll
    for (int ni = 0; ni < 4; ++ni)
      #pragma unroll
      for (int r = 0; r < 4; ++r) {
        float pe = exp2f(sa[ni][r] - mu);
        sa[ni][r] = pe;
        rs += pe;
      }
    rs += __shfl_xor(rs, 16);
    rs += __shfl_xor(rs, 32);
    lrun = lrun * corr + rs;
    mrun = mu;
  }

  bf16x8 pf[2];
  #pragma unroll
  for (int c = 0; c < 2; ++c) {
    u32 PA0 = pkbf(sa[2*c  ][0], sa[2*c  ][1]);
    u32 PA1 = pkbf(sa[2*c  ][2], sa[2*c  ][3]);
    u32 PB0 = pkbf(sa[2*c+1][0], sa[2*c+1][1]);
    u32 PB1 = pkbf(sa[2*c+1][2], sa[2*c+1][3]);
    u32 X16_0 = (u32)__shfl_xor((int)((g==2) ? PB0 : PA0), 16);
    u32 X16_1 = (u32)__shfl_xor((int)((g==2) ? PB1 : PA1), 16);
    u32 X32_0 = (u32)__shfl_xor((int)((g==0) ? PB0 : PA0), 32);
    u32 X32_1 = (u32)__shfl_xor((int)((g==0) ? PB1 : PA1), 32);
    u32 X48_0 = (u32)__shfl_xor((int)((g==1) ? PB0 : PA0), 48);
    u32 X48_1 = (u32)__shfl_xor((int)((g==1) ? PB1 : PA1), 48);
    union { u32 u[4]; bf16x8 v; } pbu;
    pbu.u[0] = (g==0) ? PA0   : (g==1) ? X48_0 : (g==2) ? X32_0 : X16_0;
    pbu.u[1] = (g==0) ? PA1   : (g==1) ? X48_1 : (g==2) ? X32_1 : X16_1;
    pbu.u[2] = (g==0) ? X16_0 : (g==1) ? X32_0 : (g==2) ? X48_0 : PB0;
    pbu.u[3] = (g==0) ? X16_1 : (g==1) ? X32_1 : (g==2) ? X48_1 : PB1;
    pf[c] = pbu.v;
  }

  if (rescale) {
    #pragma unroll
    for (int di = 0; di < 4; ++di) {
      oacc[di][0] *= corr; oacc[di][1] *= corr;
      oacc[di][2] *= corr; oacc[di][3] *= corr;
    }
  }

  #pragma unroll
  for (int c = 0; c < 2; ++c) {
    #pragma unroll
    for (int di = 0; di < 4; ++di) {
      int d = di*16 + li;
      bf16x8 vf = *(const bf16x8*)(&Vts[d*64 + (((c*4+g) ^ (d&7)))*8]);
      oacc[di] = MFMA(vf, pf[c], oacc[di]);
    }
  }
}

// ---------------- Flash attention, fine split-K (per-q-tile segments <= 8 tiles) ----------------
// causal: 80 jobs/bh (grid 2560): q-tile qt split into ceil((qt+1)/8) segs.
// k==1 (qt<8): direct write.  k>1: partial (O^,m,l) record; combine merges.
// non-causal: 64 jobs/bh (grid 2560, blocks >=2048 exit): 2 segs of 16 per q-tile.
__global__ __launch_bounds__(256, 4) void attn_kernel(
    const unsigned short* __restrict__ Qh,   // [B*H][S][64]
    const unsigned short* __restrict__ Kh,   // [B*H][S][64]
    const unsigned short* __restrict__ Vt,   // [B*H][64][S]
    const u64* __restrict__ pmask,           // [B*S][S/64]
    const u32* __restrict__ msum,            // [B*S]
    const int* __restrict__ causal_p,
    unsigned short* __restrict__ Ob,         // [B*S][H*64]
    unsigned short* __restrict__ Opart,      // [2304][4096] bf16
    float* __restrict__ Mp,                  // [2304][64]
    float* __restrict__ Lp,                  // [2304][64]
    int B, int H, int S)
{
  __shared__ unsigned short Ks [64*64];
  __shared__ unsigned short Vts[64*64];

  const int tid = threadIdx.x, w = tid >> 6, lane = tid & 63;
  const int g = lane >> 4, li = lane & 15;
  const int nkt = S >> 6;                    // 32
  const int causal = causal_p[0];
  const int j = blockIdx.x;

  int bh, qt, seg, k, t0, t1;
  if (causal) {
    bh = j / 80;
    int jj = 79 - (j - bh*80);               // reversed: big jobs first
    if (jj < 8)       { qt = jj;              seg = 0;      k = 1; }
    else if (jj < 24) { int x = jj-8;  qt = 8  + (x>>1); seg = x&1;      k = 2; }
    else if (jj < 48) { int x = jj-24; int q3 = x/3; qt = 16 + q3; seg = x - q3*3; k = 3; }
    else              { int x = jj-48; qt = 24 + (x>>2); seg = x&3;      k = 4; }
    int nt = qt + 1;
    t0 = (seg*nt)/k; t1 = ((seg+1)*nt)/k;
  } else {
    if (j >= 2048) return;
    bh = j >> 6;
    int jj = j & 63;
    qt = jj >> 1; seg = jj & 1; k = 2;
    t0 = seg*16; t1 = t0 + 16;
  }

  const int b = bh >> 4, h = bh & 15;        // H = 16
  const size_t baseK = (size_t)bh * S * 64;
  const size_t baseV = (size_t)bh * 64 * S;
  const int colk  = (lane & 7) ^ ((lane >> 3) & 7);
  const int ldrow = lane >> 3;
  const int D = H * 64;

  const int q0 = qt << 6;
  const int qg = q0 + w*16 + li;
  const unsigned short* qp = Qh + baseK + (size_t)qg*64 + g*8;
  const bf16x8 qf0 = *(const bf16x8*)(qp);
  const bf16x8 qf1 = *(const bf16x8*)(qp + 32);
  const u32 sOr = msum[(size_t)b*S + qg];
  const u64* prow = pmask + (size_t)(b*S + qg) * nkt;

  f32x4 oacc[4] = {};
  float mrun = -1e30f, lrun = 0.f;

  for (int t = t0; t < t1; ++t) {
    const int kv0 = t << 6;
    __syncthreads();
    #pragma unroll
    for (int s2 = 0; s2 < 2; ++s2) {
      int u = w*2 + s2;
      gload_lds16(Kh + baseK + (size_t)(kv0 + u*8 + ldrow)*64 + colk*8, &Ks[u*512]);
      gload_lds16(Vt + baseV + (size_t)(u*8 + ldrow)*S + kv0 + colk*8, &Vts[u*512]);
    }
    __syncthreads();
    const bool edge = (causal != 0) && (t == qt);
    const bool doMask = __any(((sOr >> t) & 1u) != 0u);
    attn_tile(Ks, Vts, qf0, qf1, mrun, lrun, oacc, edge, doMask, prow, t, kv0, qg, g, li);
  }

  if (k == 1) {
    // direct write: normalize + LDS transpose + coalesced store
    __syncthreads();
    unsigned short* scr = &Ks[w*1024];
    float rl = (lrun > 0.f) ? 1.0f / lrun : 0.f;
    #pragma unroll
    for (int di = 0; di < 4; ++di)
      #pragma unroll
      for (int r = 0; r < 4; ++r) {
        int d = di*16 + g*4 + r;
        scr[li*64 + (((d>>3) ^ (li&7)))*8 + (d&7)] = f2b(oacc[di][r] * rl);
      }
    #pragma unroll
    for (int rr = 0; rr < 2; ++rr) {
      int q = rr*8 + (lane >> 3);
      int sl = lane & 7;
      bf16x8 v = *(const bf16x8*)(&scr[q*64 + ((sl ^ (q & 7)))*8]);
      *(bf16x8*)(Ob + (size_t)(b*S + q0 + w*16 + q)*D + h*64 + sl*8) = v;
    }
  } else {
    int local;
    if (causal) {
      local = (qt < 16) ? (2*(qt-8) + seg)
            : (qt < 24) ? (16 + 3*(qt-16) + seg)
                        : (40 + 4*(qt-24) + seg);
    } else {
      local = qt*2 + seg;
    }
    const int rec = bh*72 + local;
    unsigned short* dst = Opart + (size_t)rec*4096 + (w*64 + lane)*16;
    #pragma unroll
    for (int di = 0; di < 4; ++di)
      #pragma unroll
      for (int r = 0; r < 4; ++r)
        dst[di*4 + r] = f2b(oacc[di][r]);
    if (g == 0) { Mp[rec*64 + w*16 + li] = mrun; Lp[rec*64 + w*16 + li] = lrun; }
  }
}

// ---------------- combine partial segments ----------------
__global__ __launch_bounds__(256) void attn_combine(
    const unsigned short* __restrict__ Opart,
    const float* __restrict__ Mp, const float* __restrict__ Lp,
    const int* __restrict__ causal_p,
    unsigned short* __restrict__ Ob, int H, int S)
{
  const int causal = causal_p[0];
  const int blk = blockIdx.x;
  int bh, qt, k, local0;
  if (causal) {
    if (blk >= 768) return;                  // 24 q-tiles (8..31) x 32 bh
    bh = blk / 24;
    int qq = blk - bh*24;
    qt = 8 + qq;
    if (qt < 16)      { k = 2; local0 = 2*(qt-8); }
    else if (qt < 24) { k = 3; local0 = 16 + 3*(qt-16); }
    else              { k = 4; local0 = 40 + 4*(qt-24); }
  } else {
    bh = blk >> 5; qt = blk & 31; k = 2; local0 = qt*2;
  }
  const int recb = bh*72 + local0;
  const int b = bh >> 4, h = bh & 15;
  const int tid = threadIdx.x;
  const int q = tid >> 2;
  const int dbase = (tid & 3) * 16;
  const int w = q >> 4, li = q & 15;
  const int D = H * 64;

  float ms[4], ls[4];
  float m = -1e30f;
  for (int s = 0; s < k; ++s) {
    ms[s] = Mp[(recb+s)*64 + q];
    ls[s] = Lp[(recb+s)*64 + q];
    m = fmaxf(m, ms[s]);
  }
  float wgt[4];
  float denom = 0.f;
  for (int s = 0; s < k; ++s) {
    wgt[s] = exp2f(ms[s] - m);
    denom += wgt[s] * ls[s];
  }
  float rden = (denom > 0.f) ? 1.0f/denom : 0.f;
  for (int s = 0; s < k; ++s) wgt[s] *= rden;

  unsigned short outv[16];
  #pragma unroll
  for (int kk = 0; kk < 16; ++kk) {
    int d = dbase + kk;
    int di = d >> 4, g2 = (d >> 2) & 3, r = d & 3;
    int idx = (w*64 + g2*16 + li)*16 + di*4 + r;
    float o = 0.f;
    for (int s = 0; s < k; ++s)
      o += wgt[s] * b2f(Opart[(size_t)(recb+s)*4096 + idx]);
    outv[kk] = f2b(o);
  }
  unsigned short* dst = Ob + (size_t)(b*S + qt*64 + q)*D + h*64 + dbase;
  #pragma unroll
  for (int kk = 0; kk < 16; ++kk) dst[kk] = outv[kk];
}

extern "C" void kernel_launch(void* const* d_in, const int* in_sizes, int n_in,
                              void* d_out, int out_size, void* d_ws, size_t ws_size,
                              hipStream_t stream) {
  const float* query = (const float*)d_in[0];
  const float* key_  = (const float*)d_in[1];
  const float* value = (const float*)d_in[2];
  const unsigned char* amask = (const unsigned char*)d_in[3];
  const float* Wq   = (const float*)d_in[4];
  const float* Wk   = (const float*)d_in[5];
  const float* Wv   = (const float*)d_in[6];
  const float* Wout = (const float*)d_in[7];
  const float* b_out = (const float*)d_in[8];
  const int* is_causal = (const int*)d_in[9];
  float* out = (float*)d_out;

  const int B = 2, S = 2048, D = 1024, H = 16;
  const int M = B * S;
  const size_t nx = (size_t)M * D;
  const size_t nw = (size_t)D * D;
  const int nU = B * S * (S / 64);

  unsigned short* ws = (unsigned short*)d_ws;
  unsigned short* xq = ws;                 // A = xq|xk|xv contiguous (12288x1024)
  unsigned short* xk = xq + nx;
  unsigned short* xv = xk + nx;
  unsigned short* wq = xv + nx;            // Bw = wq|wk|wv contiguous (3072x1024)
  unsigned short* wk = wq + nw;
  unsigned short* wv = wk + nw;
  unsigned short* wo = wv + nw;
  unsigned short* qb = wo + nw;            // [b][h][s][64]; kb contiguous after
  unsigned short* kb = qb + nx;            // [b][h][s][64]
  unsigned short* vt = kb + nx;            // [b][h][64][s]
  u32* msum = (u32*)(vt + nx);             // [B*S] = 64 KB
  u64* pmask = (u64*)(msum + 16384);       // 1 MB, after msum
  unsigned short* ob = xq;                 // reuse: xq dead after QKV projection
  unsigned short* Opart = xk;              // reuse: xk|xv|wq = 9,437,184 shorts exact
  float* Mp = (float*)wk;                  // reuse: wk region (2304*64 f32 = 0.59 MB)
  float* Lp = Mp + 2304*64;                // + 0.59 MB, still inside wk

  cvt7<<<dim3((unsigned)(nx/4/256), 7), 256, 0, stream>>>(
      query, key_, value, Wq, Wk, Wv, Wout,
      xq, xk, xv, wq, wk, wv, wo, (int)(nx/4), (int)(nw/4));

  qkv128s<<<dim3(3*M/128, D/128), 256, 0, stream>>>(xq, wq, qb, vt);

  pack_mask<<<512, 256, 0, stream>>>(amask, pmask, nU);
  mask_summary<<<128, 256, 0, stream>>>(pmask, msum, M, S/64);

  attn_kernel<<<dim3(2560), 256, 0, stream>>>(qb, kb, vt, pmask, msum, is_causal,
                                              ob, Opart, Mp, Lp, B, H, S);
  attn_combine<<<dim3(1024), 256, 0, stream>>>(Opart, Mp, Lp, is_causal, ob, H, S);

  gemm64x64<<<dim3(M/64, D/64), 256, 0, stream>>>(ob, wo, out, b_out, M, D, D);
}

// Round 20
// 160.140 us; speedup vs baseline: 1.1281x; 1.1281x over previous
//
#include <hip/hip_runtime.h>
#include <hip/hip_bf16.h>

typedef __attribute__((ext_vector_type(8))) short bf16x8;
typedef __attribute__((ext_vector_type(4))) float f32x4;
typedef unsigned long long u64;
typedef unsigned int u32;

#define MFMA(a,b,c) __builtin_amdgcn_mfma_f32_16x16x32_bf16(a,b,c,0,0,0)
#define NEG_INF (-__builtin_inff())
#define SCALE2 0.1803368801111244f   // 0.125 * log2(e)

__device__ __forceinline__ unsigned short f2b(float f) {
  unsigned int u = __float_as_uint(f);
  u = u + 0x7fffu + ((u >> 16) & 1u);
  return (unsigned short)(u >> 16);
}

__device__ __forceinline__ float b2f(unsigned short s) {
  unsigned int u = ((unsigned int)s) << 16;
  return __uint_as_float(u);
}

__device__ __forceinline__ u32 pkbf(float lo, float hi) {
  __hip_bfloat162 h = __float22bfloat162_rn(float2{lo, hi});
  return *reinterpret_cast<u32*>(&h);
}

__device__ __forceinline__ void gload_lds16(const unsigned short* g, unsigned short* l) {
  __builtin_amdgcn_global_load_lds((const __attribute__((address_space(1))) void*)g,
                                   (__attribute__((address_space(3))) void*)l, 16, 0, 0);
}

// ---------------- fused fp32 -> bf16 conversion for all 7 tensors ----------------
__global__ void cvt7(const float* s0, const float* s1, const float* s2,
                     const float* s3, const float* s4, const float* s5, const float* s6,
                     unsigned short* d0, unsigned short* d1, unsigned short* d2,
                     unsigned short* d3, unsigned short* d4, unsigned short* d5, unsigned short* d6,
                     int nbig, int nsmall) {
  const float* s; unsigned short* d; int n4;
  switch (blockIdx.y) {
    case 0: s=s0; d=d0; n4=nbig; break;
    case 1: s=s1; d=d1; n4=nbig; break;
    case 2: s=s2; d=d2; n4=nbig; break;
    case 3: s=s3; d=d3; n4=nsmall; break;
    case 4: s=s4; d=d4; n4=nsmall; break;
    case 5: s=s5; d=d5; n4=nsmall; break;
    default: s=s6; d=d6; n4=nsmall; break;
  }
  int i = blockIdx.x * blockDim.x + threadIdx.x;
  if (i < n4) {
    float4 v = reinterpret_cast<const float4*>(s)[i];
    ushort4 o;
    o.x = f2b(v.x); o.y = f2b(v.y); o.z = f2b(v.z); o.w = f2b(v.w);
    reinterpret_cast<ushort4*>(d)[i] = o;
  }
}

// ---------------- pack bool mask into bits ----------------
__global__ void pack_mask(const unsigned char* __restrict__ am, u64* __restrict__ pm, int nU) {
  int lane = threadIdx.x & 63;
  int wid = blockIdx.x * (blockDim.x >> 6) + (threadIdx.x >> 6);
  int stride = gridDim.x * (blockDim.x >> 6);
  for (int u = wid; u < nU; u += stride) {
    unsigned char v = am[(size_t)u * 64 + lane];
    u64 m = __ballot(v != 0);
    if (lane == 0) pm[u] = m;
  }
}

// ---------------- per-row tile summary ----------------
__global__ void mask_summary(const u64* __restrict__ pm, u32* __restrict__ ms, int rows, int nkt) {
  int lane = threadIdx.x & 63;
  int wid = (blockIdx.x * blockDim.x + threadIdx.x) >> 6;
  int nw = (gridDim.x * blockDim.x) >> 6;
  for (int rp = wid; rp < (rows >> 1); rp += nw) {
    int row = rp * 2 + (lane >> 5);
    int t = lane & 31;
    u64 v = pm[(size_t)row * nkt + t];
    u64 bm = __ballot(v != 0ULL);
    if (lane == 0)  ms[rp*2]     = (u32)bm;
    if (lane == 32) ms[rp*2 + 1] = (u32)(bm >> 32);
  }
}

// ---------------- merged QKV projection, 128x128 tile, single-buffer (m97) ----------------
__global__ __launch_bounds__(256) void qkv128s(
    const unsigned short* __restrict__ A,
    const unsigned short* __restrict__ Bw,
    unsigned short* __restrict__ Cqk,
    unsigned short* __restrict__ Cv)
{
  const int K = 1024;
  __shared__ unsigned short As[128*32];
  __shared__ unsigned short Bs[128*32];
  const int tid  = threadIdx.x;
  const int w    = tid >> 6, lane = tid & 63;
  const int wr   = w >> 1,   wc   = w & 1;
  const int g    = lane >> 4, li  = lane & 15;
  const int m0   = blockIdx.x * 128, n0 = blockIdx.y * 128;
  const int bq0  = (m0 >> 12) * 1024 + n0;

  f32x4 acc[4][4] = {};

  const int rS0 = (w*2+0)*16 + (lane>>2);
  const int rS1 = (w*2+1)*16 + (lane>>2);
  const int cS  = (lane&3)*8;
  const unsigned short* gA0 = A  + (size_t)(m0+rS0)*K + cS;
  const unsigned short* gA1 = A  + (size_t)(m0+rS1)*K + cS;
  const unsigned short* gB0 = Bw + (size_t)(bq0+rS0)*K + cS;
  const unsigned short* gB1 = Bw + (size_t)(bq0+rS1)*K + cS;
  unsigned short* lA0 = &As[(w*2+0)*512];
  unsigned short* lA1 = &As[(w*2+1)*512];
  unsigned short* lB0 = &Bs[(w*2+0)*512];
  unsigned short* lB1 = &Bs[(w*2+1)*512];

  for (int k0 = 0; k0 < K; k0 += 32) {
    gload_lds16(gA0 + k0, lA0);
    gload_lds16(gA1 + k0, lA1);
    gload_lds16(gB0 + k0, lB0);
    gload_lds16(gB1 + k0, lB1);
    __syncthreads();

    bf16x8 af[4], bf[4];
    #pragma unroll
    for (int i = 0; i < 4; ++i)
      af[i] = *(const bf16x8*)(&As[(wr*64 + i*16 + li)*32 + g*8]);
    #pragma unroll
    for (int j = 0; j < 4; ++j)
      bf[j] = *(const bf16x8*)(&Bs[(wc*64 + j*16 + li)*32 + g*8]);
    #pragma unroll
    for (int i = 0; i < 4; ++i)
      #pragma unroll
      for (int j = 0; j < 4; ++j)
        acc[i][j] = MFMA(af[i], bf[j], acc[i][j]);
    __syncthreads();
  }

  #pragma unroll
  for (int i = 0; i < 4; ++i) {
    #pragma unroll
    for (int j = 0; j < 4; ++j) {
      int col = n0 + wc*64 + j*16 + li;
      #pragma unroll
      for (int r = 0; r < 4; ++r) {
        int row = m0 + wr*64 + i*16 + g*4 + r;
        float v = acc[i][j][r];
        if (row < 8192) {
          size_t addr = (((size_t)(row >> 11) * 16 + (col >> 6)) * 2048 + (row & 2047)) * 64 + (col & 63);
          Cqk[addr] = f2b(v);
        } else {
          int tk = row & 4095;
          size_t addr = (((size_t)(tk >> 11) * 16 + (col >> 6)) * 64 + (col & 63)) * 2048 + (tk & 2047);
          Cv[addr] = f2b(v);
        }
      }
    }
  }
}

// ---------------- final projection GEMM, 64x64 tile, 2-phase dbuf ----------------
__global__ __launch_bounds__(256) void gemm64x64(
    const unsigned short* __restrict__ A,
    const unsigned short* __restrict__ Bw,
    float* __restrict__ Cf,
    const float* __restrict__ bias,
    int M, int N, int K)
{
  const int NT = 32;
  __shared__ unsigned short As[2][64*32];
  __shared__ unsigned short Bs[2][64*32];
  const int tid  = threadIdx.x;
  const int w    = tid >> 6, lane = tid & 63;
  const int wr   = w >> 1,   wc   = w & 1;
  const int g    = lane >> 4, li  = lane & 15;
  const int m0   = blockIdx.x * 64, n0 = blockIdx.y * 64;

  f32x4 acc[2][2] = {};
  const int crow = lane >> 2, ccol = (lane & 3) * 8;
  const unsigned short* gA = A  + (size_t)(m0 + w*16 + crow)*K + ccol;
  const unsigned short* gB = Bw + (size_t)(n0 + w*16 + crow)*K + ccol;

  gload_lds16(gA, &As[0][w*512]);
  gload_lds16(gB, &Bs[0][w*512]);
  __syncthreads();

  for (int t = 0; t < NT; ++t) {
    const int cur = t & 1;
    if (t + 1 < NT) {
      const int k1 = (t + 1) * 32;
      gload_lds16(gA + k1, &As[cur^1][w*512]);
      gload_lds16(gB + k1, &Bs[cur^1][w*512]);
    }
    bf16x8 af[2], bf[2];
    #pragma unroll
    for (int i = 0; i < 2; ++i)
      af[i] = *(const bf16x8*)(&As[cur][(wr*32 + i*16 + li)*32 + g*8]);
    #pragma unroll
    for (int j = 0; j < 2; ++j)
      bf[j] = *(const bf16x8*)(&Bs[cur][(wc*32 + j*16 + li)*32 + g*8]);
    #pragma unroll
    for (int i = 0; i < 2; ++i)
      #pragma unroll
      for (int j = 0; j < 2; ++j)
        acc[i][j] = MFMA(af[i], bf[j], acc[i][j]);
    __syncthreads();
  }

  #pragma unroll
  for (int i = 0; i < 2; ++i) {
    #pragma unroll
    for (int j = 0; j < 2; ++j) {
      int col = n0 + wc*32 + j*16 + li;
      #pragma unroll
      for (int r = 0; r < 4; ++r) {
        int row = m0 + wr*32 + i*16 + g*4 + r;
        Cf[(size_t)row*N + col] = acc[i][j][r] + bias[col];
      }
    }
  }
}

// ---------------- per-tile attention step (round-16 proven, verbatim) ----------------
__device__ __forceinline__ void attn_tile(
    const unsigned short* __restrict__ Ks, const unsigned short* __restrict__ Vts,
    const bf16x8& qf0, const bf16x8& qf1,
    float& mrun, float& lrun, f32x4* oacc,
    bool edge, bool doMask, const u64* __restrict__ prow,
    int t, int kv0, int qg, int g, int li)
{
  f32x4 sa[4];
  #pragma unroll
  for (int ni = 0; ni < 4; ++ni) sa[ni] = (f32x4){0.f, 0.f, 0.f, 0.f};
  #pragma unroll
  for (int ni = 0; ni < 4; ++ni) {
    int row = ni*16 + li, rx = row & 7;
    bf16x8 k0 = *(const bf16x8*)(&Ks[row*64 + ((g     ^ rx))*8]);
    bf16x8 k1 = *(const bf16x8*)(&Ks[row*64 + (((4+g) ^ rx))*8]);
    sa[ni] = MFMA(k0, qf0, sa[ni]);
    sa[ni] = MFMA(k1, qf1, sa[ni]);
  }

  float corr = 1.0f;
  bool rescale = true;

  if (!edge && !doMask) {
    float pe[4][4];
    #pragma unroll
    for (int ni = 0; ni < 4; ++ni)
      #pragma unroll
      for (int r = 0; r < 4; ++r)
        pe[ni][r] = exp2f(fmaf(sa[ni][r], SCALE2, -mrun));
    float a0 = fmaxf(sa[0][0], sa[0][1]), a1 = fmaxf(sa[0][2], sa[0][3]);
    float a2 = fmaxf(sa[1][0], sa[1][1]), a3 = fmaxf(sa[1][2], sa[1][3]);
    float a4 = fmaxf(sa[2][0], sa[2][1]), a5 = fmaxf(sa[2][2], sa[2][3]);
    float a6 = fmaxf(sa[3][0], sa[3][1]), a7 = fmaxf(sa[3][2], sa[3][3]);
    float mx = fmaxf(fmaxf(fmaxf(a0,a1), fmaxf(a2,a3)),
                     fmaxf(fmaxf(a4,a5), fmaxf(a6,a7)));
    mx = fmaxf(mx, __shfl_xor(mx, 16));
    mx = fmaxf(mx, __shfl_xor(mx, 32));
    float mxs = mx * SCALE2;
    if (__all(mxs <= mrun + 8.0f)) {
      float s0 = (pe[0][0]+pe[0][1]) + (pe[0][2]+pe[0][3]);
      float s1 = (pe[1][0]+pe[1][1]) + (pe[1][2]+pe[1][3]);
      float s2 = (pe[2][0]+pe[2][1]) + (pe[2][2]+pe[2][3]);
      float s3 = (pe[3][0]+pe[3][1]) + (pe[3][2]+pe[3][3]);
      float rs = (s0+s1) + (s2+s3);
      rs += __shfl_xor(rs, 16);
      rs += __shfl_xor(rs, 32);
      lrun += rs;
      #pragma unroll
      for (int ni = 0; ni < 4; ++ni)
        #pragma unroll
        for (int r = 0; r < 4; ++r)
          sa[ni][r] = pe[ni][r];
      rescale = false;
    } else {
      float mu = fmaxf(mrun, mxs);
      corr = exp2f(mrun - mu);
      float rs = 0.f;
      #pragma unroll
      for (int ni = 0; ni < 4; ++ni)
        #pragma unroll
        for (int r = 0; r < 4; ++r) {
          float p = exp2f(fmaf(sa[ni][r], SCALE2, -mu));
          sa[ni][r] = p;
          rs += p;
        }
      rs += __shfl_xor(rs, 16);
      rs += __shfl_xor(rs, 32);
      lrun = lrun * corr + rs;
      mrun = mu;
    }
  } else {
    u64 mrow = doMask ? prow[t] : 0ULL;
    #pragma unroll
    for (int ni = 0; ni < 4; ++ni)
      #pragma unroll
      for (int r = 0; r < 4; ++r) {
        int kvloc = ni*16 + g*4 + r;
        bool dead = (edge && (kv0 + kvloc > qg)) || ((mrow >> kvloc) & 1ULL);
        sa[ni][r] = dead ? NEG_INF : sa[ni][r] * SCALE2;
      }
    float mx = sa[0][0];
    #pragma unroll
    for (int ni = 0; ni < 4; ++ni)
      #pragma unroll
      for (int r = 0; r < 4; ++r)
        if (ni + r) mx = fmaxf(mx, sa[ni][r]);
    mx = fmaxf(mx, __shfl_xor(mx, 16));
    mx = fmaxf(mx, __shfl_xor(mx, 32));
    float mu = fmaxf(mrun, mx);
    corr = exp2f(mrun - mu);
    float rs = 0.f;
    #pragma unroll
    for (int ni = 0; ni < 4; ++ni)
      #pragma unroll
      for (int r = 0; r < 4; ++r) {
        float pe = exp2f(sa[ni][r] - mu);
        sa[ni][r] = pe;
        rs += pe;
      }
    rs += __shfl_xor(rs, 16);
    rs += __shfl_xor(rs, 32);
    lrun = lrun * corr + rs;
    mrun = mu;
  }

  bf16x8 pf[2];
  #pragma unroll
  for (int c = 0; c < 2; ++c) {
    u32 PA0 = pkbf(sa[2*c  ][0], sa[2*c  ][1]);
    u32 PA1 = pkbf(sa[2*c  ][2], sa[2*c  ][3]);
    u32 PB0 = pkbf(sa[2*c+1][0], sa[2*c+1][1]);
    u32 PB1 = pkbf(sa[2*c+1][2], sa[2*c+1][3]);
    u32 X16_0 = (u32)__shfl_xor((int)((g==2) ? PB0 : PA0), 16);
    u32 X16_1 = (u32)__shfl_xor((int)((g==2) ? PB1 : PA1), 16);
    u32 X32_0 = (u32)__shfl_xor((int)((g==0) ? PB0 : PA0), 32);
    u32 X32_1 = (u32)__shfl_xor((int)((g==0) ? PB1 : PA1), 32);
    u32 X48_0 = (u32)__shfl_xor((int)((g==1) ? PB0 : PA0), 48);
    u32 X48_1 = (u32)__shfl_xor((int)((g==1) ? PB1 : PA1), 48);
    union { u32 u[4]; bf16x8 v; } pbu;
    pbu.u[0] = (g==0) ? PA0   : (g==1) ? X48_0 : (g==2) ? X32_0 : X16_0;
    pbu.u[1] = (g==0) ? PA1   : (g==1) ? X48_1 : (g==2) ? X32_1 : X16_1;
    pbu.u[2] = (g==0) ? X16_0 : (g==1) ? X32_0 : (g==2) ? X48_0 : PB0;
    pbu.u[3] = (g==0) ? X16_1 : (g==1) ? X32_1 : (g==2) ? X48_1 : PB1;
    pf[c] = pbu.v;
  }

  if (rescale) {
    #pragma unroll
    for (int di = 0; di < 4; ++di) {
      oacc[di][0] *= corr; oacc[di][1] *= corr;
      oacc[di][2] *= corr; oacc[di][3] *= corr;
    }
  }

  #pragma unroll
  for (int c = 0; c < 2; ++c) {
    #pragma unroll
    for (int di = 0; di < 4; ++di) {
      int d = di*16 + li;
      bf16x8 vf = *(const bf16x8*)(&Vts[d*64 + (((c*4+g) ^ (d&7)))*8]);
      oacc[di] = MFMA(vf, pf[c], oacc[di]);
    }
  }
}

// ---------------- Flash attention, split-K uniform jobs (round-18 green) ----------------
__global__ __launch_bounds__(256, 4) void attn_kernel(
    const unsigned short* __restrict__ Qh,   // [B*H][S][64]
    const unsigned short* __restrict__ Kh,   // [B*H][S][64]
    const unsigned short* __restrict__ Vt,   // [B*H][64][S]
    const u64* __restrict__ pmask,           // [B*S][S/64]
    const u32* __restrict__ msum,            // [B*S]
    const int* __restrict__ causal_p,
    unsigned short* __restrict__ Ob,         // [B*S][H*64]
    unsigned short* __restrict__ Opart,      // [512*2][4096] bf16
    float* __restrict__ Mp,                  // [512*2][64]
    float* __restrict__ Lp,                  // [512*2][64]
    int B, int H, int S)
{
  __shared__ unsigned short Ks [64*64];
  __shared__ unsigned short Vts[64*64];

  const int tid = threadIdx.x, w = tid >> 6, lane = tid & 63;
  const int g = lane >> 4, li = lane & 15;
  const int nkt = S >> 6;                    // 32
  const int causal = causal_p[0];

  const int id = blockIdx.x;
  const int bh = id & 31;
  const int j  = id >> 5;                    // 0..31
  const int b = bh >> 4, h = bh & 15;
  const size_t baseK = (size_t)bh * S * 64;
  const size_t baseV = (size_t)bh * 64 * S;
  const int colk  = (lane & 7) ^ ((lane >> 3) & 7);
  const int ldrow = lane >> 3;
  const int D = H * 64;

  if (!causal) {
    const int q0 = j << 6;
    const int qg = q0 + w*16 + li;
    const unsigned short* qp = Qh + baseK + (size_t)qg*64 + g*8;
    const bf16x8 qf0 = *(const bf16x8*)(qp);
    const bf16x8 qf1 = *(const bf16x8*)(qp + 32);
    const u32 sOr = msum[(size_t)b*S + qg];
    const u64* prow = pmask + (size_t)(b*S + qg) * nkt;
    f32x4 oacc[4] = {};
    float mrun = -1e30f, lrun = 0.f;
    for (int t = 0; t < nkt; ++t) {
      const int kv0 = t << 6;
      __syncthreads();
      #pragma unroll
      for (int s2 = 0; s2 < 2; ++s2) {
        int u = w*2 + s2;
        gload_lds16(Kh + baseK + (size_t)(kv0 + u*8 + ldrow)*64 + colk*8, &Ks[u*512]);
        gload_lds16(Vt + baseV + (size_t)(u*8 + ldrow)*S + kv0 + colk*8, &Vts[u*512]);
      }
      __syncthreads();
      const bool doMask = __any(((sOr >> t) & 1u) != 0u);
      attn_tile(Ks, Vts, qf0, qf1, mrun, lrun, oacc, false, doMask, prow, t, kv0, qg, g, li);
    }
    __syncthreads();
    unsigned short* scr = &Ks[w*1024];
    float rl = (lrun > 0.f) ? 1.0f / lrun : 0.f;
    #pragma unroll
    for (int di = 0; di < 4; ++di)
      #pragma unroll
      for (int r = 0; r < 4; ++r) {
        int d = di*16 + g*4 + r;
        scr[li*64 + (((d>>3) ^ (li&7)))*8 + (d&7)] = f2b(oacc[di][r] * rl);
      }
    #pragma unroll
    for (int rr = 0; rr < 2; ++rr) {
      int q = rr*8 + (lane >> 3);
      int sl = lane & 7;
      bf16x8 v = *(const bf16x8*)(&scr[q*64 + ((sl ^ (q & 7)))*8]);
      *(bf16x8*)(Ob + (size_t)(b*S + q0 + w*16 + q)*D + h*64 + sl*8) = v;
    }
    return;
  }

  if (j < 16) {
    // ---- phase 1: q-tile j, tiles 0..j, direct write ----
    {
      const int qt = j, q0 = qt << 6;
      const int qg = q0 + w*16 + li;
      const unsigned short* qp = Qh + baseK + (size_t)qg*64 + g*8;
      const bf16x8 qf0 = *(const bf16x8*)(qp);
      const bf16x8 qf1 = *(const bf16x8*)(qp + 32);
      const u32 sOr = msum[(size_t)b*S + qg];
      const u64* prow = pmask + (size_t)(b*S + qg) * nkt;
      f32x4 oacc[4] = {};
      float mrun = -1e30f, lrun = 0.f;
      for (int t = 0; t <= qt; ++t) {
        const int kv0 = t << 6;
        __syncthreads();
        #pragma unroll
        for (int s2 = 0; s2 < 2; ++s2) {
          int u = w*2 + s2;
          gload_lds16(Kh + baseK + (size_t)(kv0 + u*8 + ldrow)*64 + colk*8, &Ks[u*512]);
          gload_lds16(Vt + baseV + (size_t)(u*8 + ldrow)*S + kv0 + colk*8, &Vts[u*512]);
        }
        __syncthreads();
        const bool edge = (t == qt);
        const bool doMask = __any(((sOr >> t) & 1u) != 0u);
        attn_tile(Ks, Vts, qf0, qf1, mrun, lrun, oacc, edge, doMask, prow, t, kv0, qg, g, li);
      }
      __syncthreads();
      unsigned short* scr = &Ks[w*1024];
      float rl = (lrun > 0.f) ? 1.0f / lrun : 0.f;
      #pragma unroll
      for (int di = 0; di < 4; ++di)
        #pragma unroll
        for (int r = 0; r < 4; ++r) {
          int d = di*16 + g*4 + r;
          scr[li*64 + (((d>>3) ^ (li&7)))*8 + (d&7)] = f2b(oacc[di][r] * rl);
        }
      #pragma unroll
      for (int rr = 0; rr < 2; ++rr) {
        int q = rr*8 + (lane >> 3);
        int sl = lane & 7;
        bf16x8 v = *(const bf16x8*)(&scr[q*64 + ((sl ^ (q & 7)))*8]);
        *(bf16x8*)(Ob + (size_t)(b*S + q0 + w*16 + q)*D + h*64 + sl*8) = v;
      }
    }
    // ---- phase 2: q-tile 31-j, tiles [0, 15-j), partial half 0 ----
    {
      const int qtH = 31 - j, q0 = qtH << 6;
      const int qg = q0 + w*16 + li;
      const unsigned short* qp = Qh + baseK + (size_t)qg*64 + g*8;
      const bf16x8 qf0 = *(const bf16x8*)(qp);
      const bf16x8 qf1 = *(const bf16x8*)(qp + 32);
      const u32 sOr = msum[(size_t)b*S + qg];
      const u64* prow = pmask + (size_t)(b*S + qg) * nkt;
      f32x4 oacc[4] = {};
      float mrun = -1e30f, lrun = 0.f;
      const int nt2 = 15 - j;
      for (int t = 0; t < nt2; ++t) {
        const int kv0 = t << 6;
        __syncthreads();
        #pragma unroll
        for (int s2 = 0; s2 < 2; ++s2) {
          int u = w*2 + s2;
          gload_lds16(Kh + baseK + (size_t)(kv0 + u*8 + ldrow)*64 + colk*8, &Ks[u*512]);
          gload_lds16(Vt + baseV + (size_t)(u*8 + ldrow)*S + kv0 + colk*8, &Vts[u*512]);
        }
        __syncthreads();
        const bool doMask = __any(((sOr >> t) & 1u) != 0u);
        attn_tile(Ks, Vts, qf0, qf1, mrun, lrun, oacc, false, doMask, prow, t, kv0, qg, g, li);
      }
      const int rec = (bh*16 + j)*2 + 0;
      unsigned short* dst = Opart + (size_t)rec*4096 + (w*64 + lane)*16;
      #pragma unroll
      for (int di = 0; di < 4; ++di)
        #pragma unroll
        for (int r = 0; r < 4; ++r)
          dst[di*4 + r] = f2b(oacc[di][r]);
      if (g == 0) { Mp[rec*64 + w*16 + li] = mrun; Lp[rec*64 + w*16 + li] = lrun; }
    }
  } else {
    // ---- single phase: q-tile 31-jp, tiles [15-jp, 31-jp], partial half 1 ----
    const int jp = j - 16;
    const int qtH = 31 - jp, q0 = qtH << 6;
    const int qg = q0 + w*16 + li;
    const unsigned short* qp = Qh + baseK + (size_t)qg*64 + g*8;
    const bf16x8 qf0 = *(const bf16x8*)(qp);
    const bf16x8 qf1 = *(const bf16x8*)(qp + 32);
    const u32 sOr = msum[(size_t)b*S + qg];
    const u64* prow = pmask + (size_t)(b*S + qg) * nkt;
    f32x4 oacc[4] = {};
    float mrun = -1e30f, lrun = 0.f;
    const int t0 = 15 - jp;
    for (int t = t0; t <= qtH; ++t) {
      const int kv0 = t << 6;
      __syncthreads();
      #pragma unroll
      for (int s2 = 0; s2 < 2; ++s2) {
        int u = w*2 + s2;
        gload_lds16(Kh + baseK + (size_t)(kv0 + u*8 + ldrow)*64 + colk*8, &Ks[u*512]);
        gload_lds16(Vt + baseV + (size_t)(u*8 + ldrow)*S + kv0 + colk*8, &Vts[u*512]);
      }
      __syncthreads();
      const bool edge = (t == qtH);
      const bool doMask = __any(((sOr >> t) & 1u) != 0u);
      attn_tile(Ks, Vts, qf0, qf1, mrun, lrun, oacc, edge, doMask, prow, t, kv0, qg, g, li);
    }
    const int rec = (bh*16 + jp)*2 + 1;
    unsigned short* dst = Opart + (size_t)rec*4096 + (w*64 + lane)*16;
    #pragma unroll
    for (int di = 0; di < 4; ++di)
      #pragma unroll
      for (int r = 0; r < 4; ++r)
        dst[di*4 + r] = f2b(oacc[di][r]);
    if (g == 0) { Mp[rec*64 + w*16 + li] = mrun; Lp[rec*64 + w*16 + li] = lrun; }
  }
}

// ---------------- combine split halves (causal only) ----------------
__global__ __launch_bounds__(256) void attn_combine(
    const unsigned short* __restrict__ Opart,
    const float* __restrict__ Mp, const float* __restrict__ Lp,
    const int* __restrict__ causal_p,
    unsigned short* __restrict__ Ob, int H, int S)
{
  if (!causal_p[0]) return;
  const int blk = blockIdx.x;                // 0..511
  const int bh = blk >> 4, qp = blk & 15;
  const int qtH = 31 - qp;
  const int hidx = bh*16 + qp;
  const int b = bh >> 4, h = bh & 15;
  const int tid = threadIdx.x;
  const int q = tid >> 2;                    // 0..63
  const int dbase = (tid & 3) * 16;
  const int w = q >> 4, li = q & 15;
  const int D = H * 64;

  const int recA = hidx*2 + 0, recB = hidx*2 + 1;
  float mA = Mp[recA*64 + q], mB = Mp[recB*64 + q];
  float lA = Lp[recA*64 + q], lB = Lp[recB*64 + q];
  float m = fmaxf(mA, mB);
  float sA = exp2f(mA - m), sB = exp2f(mB - m);
  float denom = sA*lA + sB*lB;
  float rden = (denom > 0.f) ? 1.0f/denom : 0.f;
  sA *= rden; sB *= rden;

  const unsigned short* pA = Opart + (size_t)recA*4096;
  const unsigned short* pB = Opart + (size_t)recB*4096;
  unsigned short outv[16];
  #pragma unroll
  for (int k = 0; k < 16; ++k) {
    int d = dbase + k;
    int di = d >> 4, g2 = (d >> 2) & 3, r = d & 3;
    int idx = (w*64 + g2*16 + li)*16 + di*4 + r;
    float o = sA * b2f(pA[idx]) + sB * b2f(pB[idx]);
    outv[k] = f2b(o);
  }
  unsigned short* dst = Ob + (size_t)(b*S + qtH*64 + q)*D + h*64 + dbase;
  #pragma unroll
  for (int k = 0; k < 16; ++k) dst[k] = outv[k];
}

extern "C" void kernel_launch(void* const* d_in, const int* in_sizes, int n_in,
                              void* d_out, int out_size, void* d_ws, size_t ws_size,
                              hipStream_t stream) {
  const float* query = (const float*)d_in[0];
  const float* key_  = (const float*)d_in[1];
  const float* value = (const float*)d_in[2];
  const unsigned char* amask = (const unsigned char*)d_in[3];
  const float* Wq   = (const float*)d_in[4];
  const float* Wk   = (const float*)d_in[5];
  const float* Wv   = (const float*)d_in[6];
  const float* Wout = (const float*)d_in[7];
  const float* b_out = (const float*)d_in[8];
  const int* is_causal = (const int*)d_in[9];
  float* out = (float*)d_out;

  const int B = 2, S = 2048, D = 1024, H = 16;
  const int M = B * S;
  const size_t nx = (size_t)M * D;
  const size_t nw = (size_t)D * D;
  const int nU = B * S * (S / 64);

  unsigned short* ws = (unsigned short*)d_ws;
  unsigned short* xq = ws;                 // A = xq|xk|xv contiguous (12288x1024)
  unsigned short* xk = xq + nx;
  unsigned short* xv = xk + nx;
  unsigned short* wq = xv + nx;            // Bw = wq|wk|wv contiguous (3072x1024)
  unsigned short* wk = wq + nw;
  unsigned short* wv = wk + nw;
  unsigned short* wo = wv + nw;
  unsigned short* qb = wo + nw;            // [b][h][s][64]; kb contiguous after
  unsigned short* kb = qb + nx;            // [b][h][s][64]
  unsigned short* vt = kb + nx;            // [b][h][64][s]
  u32* msum = (u32*)(vt + nx);             // [B*S]
  unsigned short* ob = xq;                 // reuse: xq dead after QKV projection
  u64* pmask = (u64*)xv;                   // reuse: xv dead after QKV projection
  unsigned short* Opart = xk;              // reuse: xk dead after QKV (1024*4096 = nx exact)
  float* Mp = (float*)wq;                  // reuse: wq dead after QKV (64K floats)
  float* Lp = Mp + 1024*64;                // +64K floats, still inside wq region

  cvt7<<<dim3((unsigned)(nx/4/256), 7), 256, 0, stream>>>(
      query, key_, value, Wq, Wk, Wv, Wout,
      xq, xk, xv, wq, wk, wv, wo, (int)(nx/4), (int)(nw/4));

  qkv128s<<<dim3(3*M/128, D/128), 256, 0, stream>>>(xq, wq, qb, vt);

  pack_mask<<<512, 256, 0, stream>>>(amask, pmask, nU);
  mask_summary<<<128, 256, 0, stream>>>(pmask, msum, M, S/64);

  attn_kernel<<<dim3(1024), 256, 0, stream>>>(qb, kb, vt, pmask, msum, is_causal,
                                              ob, Opart, Mp, Lp, B, H, S);
  attn_combine<<<dim3(512), 256, 0, stream>>>(Opart, Mp, Lp, is_causal, ob, H, S);

  gemm64x64<<<dim3(M/64, D/64), 256, 0, stream>>>(ob, wo, out, b_out, M, D, D);
}